// Round 7
// baseline (176.201 us; speedup 1.0000x reference)
//
#include <hip/hip_runtime.h>
#include <math.h>
#include <stdint.h>

#define NB 4
#define LQ 768
#define NH 8
#define NE 64
#define ND 192   // 3*E augmented feature dim
#define TEMP 0.125f

typedef _Float16 f16;
typedef __attribute__((ext_vector_type(8))) _Float16 f16x8;
typedef __attribute__((ext_vector_type(4))) float f32x4;

// Async global->LDS 16B: HW writes lds_base + lane*16. lds_base wave-uniform.
__device__ __forceinline__ void stage16(f16* lds_base, const f16* g, int lane) {
#if __has_builtin(__builtin_amdgcn_global_load_lds)
    __builtin_amdgcn_global_load_lds(
        (const __attribute__((address_space(1))) uint32_t*)g,
        (__attribute__((address_space(3))) uint32_t*)lds_base, 16, 0, 0);
#else
    *(uint4*)((char*)lds_base + lane * 16) = *(const uint4*)g;
#endif
}

// ---------------- fused prep (blocks 0..767) + V transpose (768..1151) ----------------
__global__ __launch_bounds__(256) void sinattn_prepvt(
    const float* __restrict__ Q, const float* __restrict__ K,
    const float* __restrict__ V,
    const float* __restrict__ freqs, const float* __restrict__ offsets,
    const float* __restrict__ gains, const float* __restrict__ gate,
    f16* __restrict__ Qf, f16* __restrict__ Kf, f16* __restrict__ Vt)
{
    if (blockIdx.x < 768) {
        int idx = blockIdx.x * 256 + threadIdx.x;   // ((n*L+l)*8 + h)*8 + eg
        int eg = idx & 7, e0 = eg << 3;
        int h  = (idx >> 3) & 7;
        int t  = idx >> 6;                          // n*L + l
        int l  = t % LQ;
        int n  = t / LQ;
        int nh = (n << 3) | h;
        int he = (h << 6) | e0;

        const float* qp = Q + (size_t)idx * 8;
        const float* kp = K + (size_t)idx * 8;
        float4 q0 = *(const float4*)qp, q1 = *(const float4*)(qp + 4);
        float4 k0 = *(const float4*)kp, k1 = *(const float4*)(kp + 4);
        float qv[8] = {q0.x,q0.y,q0.z,q0.w, q1.x,q1.y,q1.z,q1.w};
        float kv[8] = {k0.x,k0.y,k0.z,k0.w, k1.x,k1.y,k1.z,k1.w};

        float4 fA = *(const float4*)(freqs   + he), fB = *(const float4*)(freqs   + he + 4);
        float4 oA = *(const float4*)(offsets + he), oB = *(const float4*)(offsets + he + 4);
        float4 gA = *(const float4*)(gains   + he), gB = *(const float4*)(gains   + he + 4);
        float4 tA = *(const float4*)(gate    + he), tB = *(const float4*)(gate    + he + 4);
        float fv[8] = {fA.x,fA.y,fA.z,fA.w, fB.x,fB.y,fB.z,fB.w};
        float ov[8] = {oA.x,oA.y,oA.z,oA.w, oB.x,oB.y,oB.z,oB.w};
        float gv[8] = {gA.x,gA.y,gA.z,gA.w, gB.x,gB.y,gB.z,gB.w};
        float tv[8] = {tA.x,tA.y,tA.z,tA.w, tB.x,tB.y,tB.z,tB.w};

        f16x8 oq0, oq1, oq2, ok0, ok1, ok2;
        float lf = (float)l;
        #pragma unroll
        for (int j = 0; j < 8; ++j) {
            float f  = 0.5f / (1.0f + __expf(-fv[j]));
            float gn = gv[j];
            float sp = (gn > 15.0f) ? gn : __logf(1.0f + __expf(gn));
            float gt = tv[j];
            float a  = (1.0f - gt) * sp * sp;
            float fh = __uint_as_float(__float_as_uint(f) & 0xFFFFF000u);
            float fl = f - fh;
            float t0 = lf * fh;
            float tr = t0 - floorf(t0);
            tr = __builtin_fmaf(lf, fl, tr);
            float pk = 6.28318530717958647f * tr;
            float pq = pk + ov[j];
            float sq = __sinf(pq), cq = __cosf(pq);
            float sk = __sinf(pk), ck = __cosf(pk);
            oq0[j] = (f16)(qv[j] * a * cq);
            oq1[j] = (f16)(qv[j] * a * sq);
            oq2[j] = (f16)(qv[j] * gt);
            ok0[j] = (f16)(kv[j] * ck);
            ok1[j] = (f16)(kv[j] * sk);
            ok2[j] = (f16)(kv[j]);
        }
        size_t base = ((size_t)nh * LQ + l) * ND + e0;
        *(f16x8*)(Qf + base)          = oq0;
        *(f16x8*)(Qf + base + NE)     = oq1;
        *(f16x8*)(Qf + base + 2*NE)   = oq2;
        *(f16x8*)(Kf + base)          = ok0;
        *(f16x8*)(Kf + base + NE)     = ok1;
        *(f16x8*)(Kf + base + 2*NE)   = ok2;
    } else {
        __shared__ f16 tile[64][72];
        int b = blockIdx.x - 768;
        int st = b % 12, nh = b / 12;
        int n = nh >> 3, h = nh & 7;
        int s0 = st * 64;
        int tid = threadIdx.x;

        int sl = tid >> 2, e0 = (tid & 3) << 4;
        const float4* vp = (const float4*)(V + ((size_t)(n * LQ + s0 + sl) * NH + h) * NE + e0);
        float4 a0 = vp[0], a1 = vp[1], a2 = vp[2], a3 = vp[3];
        float vv[16] = { a0.x,a0.y,a0.z,a0.w, a1.x,a1.y,a1.z,a1.w,
                         a2.x,a2.y,a2.z,a2.w, a3.x,a3.y,a3.z,a3.w };
        #pragma unroll
        for (int j = 0; j < 16; ++j) tile[e0 + j][sl] = (f16)vv[j];
        __syncthreads();

        int er = tid >> 2, sc = tid & 3;
        f16* op = Vt + ((size_t)nh * NE + er) * LQ + s0 + sc * 16;
        *(uint4*)op       = *(const uint4*)&tile[er][sc * 16];
        *(uint4*)(op + 8) = *(const uint4*)&tile[er][sc * 16 + 8];
    }
}

// ---------------- flash: 16 rows/wave, single-buffer LDS K, 3 blocks/CU ----------------
// grid 768 = 32 nh x 12 q-tiles(64) x 2 K-halves = exactly 3 blocks/CU, all
// co-resident (LDS 33 KB). Single sK buffer, 2 barriers/chunk; the chunk g+1
// DMA is issued after the read-barrier and lands during softmax+PV.
// V/mask/keylen direct from L2. Emits unnormalized O + (m,l) per row.
__global__ __launch_bounds__(256, 4) void sinattn_flash(
    const f16* __restrict__ Qf, const f16* __restrict__ Kf, const f16* __restrict__ Vt,
    const float* __restrict__ mask, const float* __restrict__ keylen,
    float* __restrict__ Op, float* __restrict__ Mp, float* __restrict__ Lp)
{
    __shared__ __attribute__((aligned(16))) f16 sK[64 * 24 * 8];   // 24 KB
    __shared__ __attribute__((aligned(16))) f16 sP[4][16 * 72];    // 9.2 KB

    int tid  = threadIdx.x;
    int wv   = tid >> 6;
    int wvu  = __builtin_amdgcn_readfirstlane(wv);
    int lane = tid & 63;
    int grp  = lane >> 4;
    int r16  = lane & 15;
    int swz  = r16 & 7;

    int bid  = blockIdx.x;
    int nh   = bid & 31;          // XCD-local: bid%8 == nh%8 for all 24 blocks of nh
    int rest = bid >> 5;          // 0..23
    int lt   = rest >> 1;         // 0..11
    int half = rest & 1;
    int n    = nh >> 3;
    int l0   = lt * 64;
    int c0   = half * 6;

    const f16* Kb = Kf + (size_t)nh * LQ * ND;
    const f16* Vb = Vt + (size_t)nh * NE * LQ;

    // per-lane swizzled global offsets for K staging (1536 16B-chunks, 6/thread)
    int goffK[6];
    #pragma unroll
    for (int i = 0; i < 6; ++i) {
        int p = i * 256 + wv * 64 + lane;
        int r = p / 24, c = p - r * 24;
        int cl = (c & ~7) | ((c & 7) ^ (r & 7));
        goffK[i] = r * ND + cl * 8;
    }

    // issue chunk c0 DMA immediately (lands while qf loads / init run)
    {
        const f16* kg = Kb + (size_t)c0 * 64 * ND;
        #pragma unroll
        for (int i = 0; i < 6; ++i)
            stage16(&sK[(i * 256 + wvu * 64) * 8], kg + goffK[i], lane);
    }

    // Q fragments (A-layout: row=r16, k=d0*32+grp*8+j), live whole kernel
    f16x8 qf[6];
    {
        size_t rbase = ((size_t)nh * LQ + l0 + wv * 16 + r16) * ND + grp * 8;
        #pragma unroll
        for (int d0 = 0; d0 < 6; ++d0)
            qf[d0] = *(const f16x8*)(Qf + rbase + d0 * 32);
    }

    float m_i[4], l_i[4];
    f32x4 O[4];
    #pragma unroll
    for (int rr = 0; rr < 4; ++rr) { m_i[rr] = -INFINITY; l_i[rr] = 0.f; }
    #pragma unroll
    for (int tt = 0; tt < 4; ++tt)
        #pragma unroll
        for (int rr = 0; rr < 4; ++rr) O[tt][rr] = 0.f;

    for (int g = 0; g < 6; ++g) {
        int s0 = (c0 + g) * 64;
        __syncthreads();   // barrier 1: chunk g's DMA landed (vmcnt drained)

        // early-issue per-wave global loads for this chunk (consumed later)
        float klv[4];
        #pragma unroll
        for (int j = 0; j < 4; ++j) klv[j] = keylen[n * LQ + s0 + j * 16 + r16];
        f16x8 vb[2][4];
        #pragma unroll
        for (int kk = 0; kk < 2; ++kk)
            #pragma unroll
            for (int tt = 0; tt < 4; ++tt)
                vb[kk][tt] = *(const f16x8*)(Vb + (size_t)(tt * 16 + r16) * LQ
                                             + s0 + kk * 32 + grp * 8);

        // S = Q'.K'^T from LDS
        f32x4 st[4];
        #pragma unroll
        for (int j = 0; j < 4; ++j)
            #pragma unroll
            for (int rr = 0; rr < 4; ++rr) st[j][rr] = 0.f;
        #pragma unroll
        for (int d0 = 0; d0 < 6; ++d0) {
            #pragma unroll
            for (int j = 0; j < 4; ++j) {
                int cc = d0 * 4 + grp;
                int cl = (cc & ~7) | ((cc & 7) ^ swz);
                f16x8 bf = *(const f16x8*)&sK[((j * 16 + r16) * 24 + cl) * 8];
                st[j] = __builtin_amdgcn_mfma_f32_16x16x32_f16(qf[d0], bf, st[j], 0, 0, 0);
            }
        }

        __syncthreads();   // barrier 2: all waves done reading sK

        if (g < 5) {       // DMA chunk g+1 into sK; lands during softmax+PV
            const f16* kg = Kb + (size_t)(s0 + 64) * ND;
            #pragma unroll
            for (int i = 0; i < 6; ++i)
                stage16(&sK[(i * 256 + wvu * 64) * 8], kg + goffK[i], lane);
        }

        // online softmax (C layout: col=r16+16j, row=grp*4+rr)
        #pragma unroll
        for (int rr = 0; rr < 4; ++rr) {
            int lrow = l0 + wv * 16 + grp * 4 + rr;
            float lg[4];
            float mx = -INFINITY;
            #pragma unroll
            for (int j = 0; j < 4; ++j) {
                lg[j] = TEMP * (st[j][rr] + mask[lrow * LQ + s0 + j * 16 + r16] + klv[j]);
                mx = fmaxf(mx, lg[j]);
            }
            #pragma unroll
            for (int d = 1; d < 16; d <<= 1) mx = fmaxf(mx, __shfl_xor(mx, d));
            float mnew  = fmaxf(m_i[rr], mx);
            float alpha = __expf(m_i[rr] - mnew);
            float rs = 0.f;
            #pragma unroll
            for (int j = 0; j < 4; ++j) {
                float p = __expf(lg[j] - mnew);
                rs += p;
                sP[wv][(grp * 4 + rr) * 72 + j * 16 + r16] = (f16)p;
            }
            #pragma unroll
            for (int d = 1; d < 16; d <<= 1) rs += __shfl_xor(rs, d);
            l_i[rr] = l_i[rr] * alpha + rs;
            m_i[rr] = mnew;
            #pragma unroll
            for (int tt = 0; tt < 4; ++tt) O[tt][rr] *= alpha;
        }
        // no barrier: sP strictly per-wave; in-wave LDS ordering via lgkmcnt

        // O += P.V
        #pragma unroll
        for (int kk = 0; kk < 2; ++kk) {
            f16x8 pa = *(const f16x8*)&sP[wv][r16 * 72 + kk * 32 + grp * 8];
            #pragma unroll
            for (int tt = 0; tt < 4; ++tt)
                O[tt] = __builtin_amdgcn_mfma_f32_16x16x32_f16(pa, vb[kk][tt], O[tt], 0, 0, 0);
        }
    }

    // epilogue: unnormalized O + per-row (m, l)
    #pragma unroll
    for (int rr = 0; rr < 4; ++rr) {
        int lrow = l0 + wv * 16 + grp * 4 + rr;
        size_t prow = (size_t)(half * 32 + nh) * LQ + lrow;
        float* op = Op + prow * NE;
        #pragma unroll
        for (int tt = 0; tt < 4; ++tt)
            op[tt * 16 + r16] = O[tt][rr];
        if (r16 == 0) {
            Mp[prow] = m_i[rr];
            Lp[prow] = l_i[rr];
        }
    }
}

// ---------------- merge: combine the two split-K halves (exact) ----------------
__global__ __launch_bounds__(256) void sinattn_merge(
    const float* __restrict__ Op, const float* __restrict__ Mp,
    const float* __restrict__ Lp, float* __restrict__ out)
{
    int idx = blockIdx.x * 256 + threadIdx.x;   // ((n*L+l)*H+h)*E+e
    if (idx >= NB * LQ * NH * NE) return;
    int e = idx & 63;
    int h = (idx >> 6) & 7;
    int t = idx >> 9;
    int l = t % LQ;
    int n = t / LQ;
    int nh = (n << 3) | h;
    int row = nh * LQ + l;
    const int HOFF = 32 * LQ;

    float m0 = Mp[row],        m1 = Mp[HOFF + row];
    float l0 = Lp[row],        l1 = Lp[HOFF + row];
    float mm = fmaxf(m0, m1);
    float a0 = __expf(m0 - mm), a1 = __expf(m1 - mm);
    float denom = l0 * a0 + l1 * a1;
    float o0 = Op[(size_t)row * NE + e];
    float o1 = Op[(size_t)(HOFF + row) * NE + e];
    out[idx] = (o0 * a0 + o1 * a1) / denom;
}

extern "C" void kernel_launch(void* const* d_in, const int* in_sizes, int n_in,
                              void* d_out, int out_size, void* d_ws, size_t ws_size,
                              hipStream_t stream)
{
    const float* Q      = (const float*)d_in[0];
    const float* K      = (const float*)d_in[1];
    const float* V      = (const float*)d_in[2];
    const float* mask   = (const float*)d_in[3];
    const float* keylen = (const float*)d_in[4];
    const float* freqs  = (const float*)d_in[5];
    const float* offs   = (const float*)d_in[6];
    const float* gains  = (const float*)d_in[7];
    const float* gate   = (const float*)d_in[8];
    float* out = (float*)d_out;

    const size_t P = (size_t)NB * NH * LQ * ND;   // 4.72M f16 / plane
    f16* Qf = (f16*)d_ws;
    f16* Kf = Qf + P;
    f16* Vt = Kf + P;                             // 1.57M f16
    float* Op = (float*)(Vt + (size_t)NB * NH * NE * LQ);  // 2*32*768*64 f32
    float* Mp = Op + (size_t)2 * 32 * LQ * NE;
    float* Lp = Mp + (size_t)2 * 32 * LQ;

    sinattn_prepvt<<<1152, 256, 0, stream>>>(Q, K, V, freqs, offs, gains, gate,
                                             Qf, Kf, Vt);
    sinattn_flash<<<768, 256, 0, stream>>>(Qf, Kf, Vt, mask, keylen, Op, Mp, Lp);
    sinattn_merge<<<6144, 256, 0, stream>>>(Op, Mp, Lp, out);
}

// Round 8
// 137.406 us; speedup vs baseline: 1.2823x; 1.2823x over previous
//
#include <hip/hip_runtime.h>
#include <math.h>
#include <stdint.h>

#define NB 4
#define LQ 768
#define NH 8
#define NE 64
#define ND 192   // 3*E augmented feature dim
#define TEMP 0.125f

typedef _Float16 f16;
typedef __attribute__((ext_vector_type(8))) _Float16 f16x8;
typedef __attribute__((ext_vector_type(4))) float f32x4;

// Async global->LDS 16B: HW writes lds_base + lane*16. lds_base wave-uniform.
__device__ __forceinline__ void stage16(f16* lds_base, const f16* g, int lane) {
#if __has_builtin(__builtin_amdgcn_global_load_lds)
    __builtin_amdgcn_global_load_lds(
        (const __attribute__((address_space(1))) uint32_t*)g,
        (__attribute__((address_space(3))) uint32_t*)lds_base, 16, 0, 0);
#else
    *(uint4*)((char*)lds_base + lane * 16) = *(const uint4*)g;
#endif
}

// ---------------- fused prep (blocks 0..767) + V transpose (768..1151) ----------------
__global__ __launch_bounds__(256) void sinattn_prepvt(
    const float* __restrict__ Q, const float* __restrict__ K,
    const float* __restrict__ V,
    const float* __restrict__ freqs, const float* __restrict__ offsets,
    const float* __restrict__ gains, const float* __restrict__ gate,
    f16* __restrict__ Qf, f16* __restrict__ Kf, f16* __restrict__ Vt)
{
    if (blockIdx.x < 768) {
        int idx = blockIdx.x * 256 + threadIdx.x;   // ((n*L+l)*8 + h)*8 + eg
        int eg = idx & 7, e0 = eg << 3;
        int h  = (idx >> 3) & 7;
        int t  = idx >> 6;                          // n*L + l
        int l  = t % LQ;
        int n  = t / LQ;
        int nh = (n << 3) | h;
        int he = (h << 6) | e0;

        const float* qp = Q + (size_t)idx * 8;
        const float* kp = K + (size_t)idx * 8;
        float4 q0 = *(const float4*)qp, q1 = *(const float4*)(qp + 4);
        float4 k0 = *(const float4*)kp, k1 = *(const float4*)(kp + 4);
        float qv[8] = {q0.x,q0.y,q0.z,q0.w, q1.x,q1.y,q1.z,q1.w};
        float kv[8] = {k0.x,k0.y,k0.z,k0.w, k1.x,k1.y,k1.z,k1.w};

        float4 fA = *(const float4*)(freqs   + he), fB = *(const float4*)(freqs   + he + 4);
        float4 oA = *(const float4*)(offsets + he), oB = *(const float4*)(offsets + he + 4);
        float4 gA = *(const float4*)(gains   + he), gB = *(const float4*)(gains   + he + 4);
        float4 tA = *(const float4*)(gate    + he), tB = *(const float4*)(gate    + he + 4);
        float fv[8] = {fA.x,fA.y,fA.z,fA.w, fB.x,fB.y,fB.z,fB.w};
        float ov[8] = {oA.x,oA.y,oA.z,oA.w, oB.x,oB.y,oB.z,oB.w};
        float gv[8] = {gA.x,gA.y,gA.z,gA.w, gB.x,gB.y,gB.z,gB.w};
        float tv[8] = {tA.x,tA.y,tA.z,tA.w, tB.x,tB.y,tB.z,tB.w};

        f16x8 oq0, oq1, oq2, ok0, ok1, ok2;
        float lf = (float)l;
        #pragma unroll
        for (int j = 0; j < 8; ++j) {
            float f  = 0.5f / (1.0f + __expf(-fv[j]));
            float gn = gv[j];
            float sp = (gn > 15.0f) ? gn : __logf(1.0f + __expf(gn));
            float gt = tv[j];
            float a  = (1.0f - gt) * sp * sp;
            float fh = __uint_as_float(__float_as_uint(f) & 0xFFFFF000u);
            float fl = f - fh;
            float t0 = lf * fh;
            float tr = t0 - floorf(t0);
            tr = __builtin_fmaf(lf, fl, tr);
            float pk = 6.28318530717958647f * tr;
            float pq = pk + ov[j];
            float sq = __sinf(pq), cq = __cosf(pq);
            float sk = __sinf(pk), ck = __cosf(pk);
            oq0[j] = (f16)(qv[j] * a * cq);
            oq1[j] = (f16)(qv[j] * a * sq);
            oq2[j] = (f16)(qv[j] * gt);
            ok0[j] = (f16)(kv[j] * ck);
            ok1[j] = (f16)(kv[j] * sk);
            ok2[j] = (f16)(kv[j]);
        }
        size_t base = ((size_t)nh * LQ + l) * ND + e0;
        *(f16x8*)(Qf + base)          = oq0;
        *(f16x8*)(Qf + base + NE)     = oq1;
        *(f16x8*)(Qf + base + 2*NE)   = oq2;
        *(f16x8*)(Kf + base)          = ok0;
        *(f16x8*)(Kf + base + NE)     = ok1;
        *(f16x8*)(Kf + base + 2*NE)   = ok2;
    } else {
        __shared__ f16 tile[64][72];
        int b = blockIdx.x - 768;
        int st = b % 12, nh = b / 12;
        int n = nh >> 3, h = nh & 7;
        int s0 = st * 64;
        int tid = threadIdx.x;

        int sl = tid >> 2, e0 = (tid & 3) << 4;
        const float4* vp = (const float4*)(V + ((size_t)(n * LQ + s0 + sl) * NH + h) * NE + e0);
        float4 a0 = vp[0], a1 = vp[1], a2 = vp[2], a3 = vp[3];
        float vv[16] = { a0.x,a0.y,a0.z,a0.w, a1.x,a1.y,a1.z,a1.w,
                         a2.x,a2.y,a2.z,a2.w, a3.x,a3.y,a3.z,a3.w };
        #pragma unroll
        for (int j = 0; j < 16; ++j) tile[e0 + j][sl] = (f16)vv[j];
        __syncthreads();

        int er = tid >> 2, sc = tid & 3;
        f16* op = Vt + ((size_t)nh * NE + er) * LQ + s0 + sc * 16;
        *(uint4*)op       = *(const uint4*)&tile[er][sc * 16];
        *(uint4*)(op + 8) = *(const uint4*)&tile[er][sc * 16 + 8];
    }
}

// ---------------- flash: 16 rows/wave, single-buffer LDS K, 3 blocks/CU ----------------
// grid 768 = 32 nh x 12 q-tiles(64) x 2 K-halves = exactly 3 blocks/CU, all
// co-resident (LDS 33 KB; launch_bounds(256,3) -> VGPR cap 168, no spill —
// (256,4) in R7 clamped to 64 VGPRs and spilled ~50 MB to scratch).
// Single sK buffer, 2 barriers/chunk; chunk g+1 DMA issued after the
// read-barrier lands during softmax+PV. V/mask/keylen direct from L2.
__global__ __launch_bounds__(256, 3) void sinattn_flash(
    const f16* __restrict__ Qf, const f16* __restrict__ Kf, const f16* __restrict__ Vt,
    const float* __restrict__ mask, const float* __restrict__ keylen,
    float* __restrict__ Op, float* __restrict__ Mp, float* __restrict__ Lp)
{
    __shared__ __attribute__((aligned(16))) f16 sK[64 * 24 * 8];   // 24 KB
    __shared__ __attribute__((aligned(16))) f16 sP[4][16 * 72];    // 9.2 KB

    int tid  = threadIdx.x;
    int wv   = tid >> 6;
    int wvu  = __builtin_amdgcn_readfirstlane(wv);
    int lane = tid & 63;
    int grp  = lane >> 4;
    int r16  = lane & 15;
    int swz  = r16 & 7;

    int bid  = blockIdx.x;
    int nh   = bid & 31;          // XCD-local: bid%8 == nh%8 for all 24 blocks of nh
    int rest = bid >> 5;          // 0..23
    int lt   = rest >> 1;         // 0..11
    int half = rest & 1;
    int n    = nh >> 3;
    int l0   = lt * 64;
    int c0   = half * 6;

    const f16* Kb = Kf + (size_t)nh * LQ * ND;
    const f16* Vb = Vt + (size_t)nh * NE * LQ;

    // per-lane swizzled global offsets for K staging (1536 16B-chunks, 6/thread)
    int goffK[6];
    #pragma unroll
    for (int i = 0; i < 6; ++i) {
        int p = i * 256 + wv * 64 + lane;
        int r = p / 24, c = p - r * 24;
        int cl = (c & ~7) | ((c & 7) ^ (r & 7));
        goffK[i] = r * ND + cl * 8;
    }

    // issue chunk c0 DMA immediately (lands while qf loads / init run)
    {
        const f16* kg = Kb + (size_t)c0 * 64 * ND;
        #pragma unroll
        for (int i = 0; i < 6; ++i)
            stage16(&sK[(i * 256 + wvu * 64) * 8], kg + goffK[i], lane);
    }

    // Q fragments (A-layout: row=r16, k=d0*32+grp*8+j), live whole kernel
    f16x8 qf[6];
    {
        size_t rbase = ((size_t)nh * LQ + l0 + wv * 16 + r16) * ND + grp * 8;
        #pragma unroll
        for (int d0 = 0; d0 < 6; ++d0)
            qf[d0] = *(const f16x8*)(Qf + rbase + d0 * 32);
    }

    float m_i[4], l_i[4];
    f32x4 O[4];
    #pragma unroll
    for (int rr = 0; rr < 4; ++rr) { m_i[rr] = -INFINITY; l_i[rr] = 0.f; }
    #pragma unroll
    for (int tt = 0; tt < 4; ++tt)
        #pragma unroll
        for (int rr = 0; rr < 4; ++rr) O[tt][rr] = 0.f;

    for (int g = 0; g < 6; ++g) {
        int s0 = (c0 + g) * 64;
        __syncthreads();   // barrier 1: chunk g's DMA landed (vmcnt drained)

        // early-issue per-wave global loads for this chunk (consumed later)
        float klv[4];
        #pragma unroll
        for (int j = 0; j < 4; ++j) klv[j] = keylen[n * LQ + s0 + j * 16 + r16];
        f16x8 vb[2][4];
        #pragma unroll
        for (int kk = 0; kk < 2; ++kk)
            #pragma unroll
            for (int tt = 0; tt < 4; ++tt)
                vb[kk][tt] = *(const f16x8*)(Vb + (size_t)(tt * 16 + r16) * LQ
                                             + s0 + kk * 32 + grp * 8);

        // S = Q'.K'^T from LDS
        f32x4 st[4];
        #pragma unroll
        for (int j = 0; j < 4; ++j)
            #pragma unroll
            for (int rr = 0; rr < 4; ++rr) st[j][rr] = 0.f;
        #pragma unroll
        for (int d0 = 0; d0 < 6; ++d0) {
            #pragma unroll
            for (int j = 0; j < 4; ++j) {
                int cc = d0 * 4 + grp;
                int cl = (cc & ~7) | ((cc & 7) ^ swz);
                f16x8 bf = *(const f16x8*)&sK[((j * 16 + r16) * 24 + cl) * 8];
                st[j] = __builtin_amdgcn_mfma_f32_16x16x32_f16(qf[d0], bf, st[j], 0, 0, 0);
            }
        }

        __syncthreads();   // barrier 2: all waves done reading sK

        if (g < 5) {       // DMA chunk g+1 into sK; lands during softmax+PV
            const f16* kg = Kb + (size_t)(s0 + 64) * ND;
            #pragma unroll
            for (int i = 0; i < 6; ++i)
                stage16(&sK[(i * 256 + wvu * 64) * 8], kg + goffK[i], lane);
        }

        // online softmax (C layout: col=r16+16j, row=grp*4+rr)
        #pragma unroll
        for (int rr = 0; rr < 4; ++rr) {
            int lrow = l0 + wv * 16 + grp * 4 + rr;
            float lg[4];
            float mx = -INFINITY;
            #pragma unroll
            for (int j = 0; j < 4; ++j) {
                lg[j] = TEMP * (st[j][rr] + mask[lrow * LQ + s0 + j * 16 + r16] + klv[j]);
                mx = fmaxf(mx, lg[j]);
            }
            #pragma unroll
            for (int d = 1; d < 16; d <<= 1) mx = fmaxf(mx, __shfl_xor(mx, d));
            float mnew  = fmaxf(m_i[rr], mx);
            float alpha = __expf(m_i[rr] - mnew);
            float rs = 0.f;
            #pragma unroll
            for (int j = 0; j < 4; ++j) {
                float p = __expf(lg[j] - mnew);
                rs += p;
                sP[wv][(grp * 4 + rr) * 72 + j * 16 + r16] = (f16)p;
            }
            #pragma unroll
            for (int d = 1; d < 16; d <<= 1) rs += __shfl_xor(rs, d);
            l_i[rr] = l_i[rr] * alpha + rs;
            m_i[rr] = mnew;
            #pragma unroll
            for (int tt = 0; tt < 4; ++tt) O[tt][rr] *= alpha;
        }
        // no barrier: sP strictly per-wave; in-wave LDS ordering via lgkmcnt

        // O += P.V
        #pragma unroll
        for (int kk = 0; kk < 2; ++kk) {
            f16x8 pa = *(const f16x8*)&sP[wv][r16 * 72 + kk * 32 + grp * 8];
            #pragma unroll
            for (int tt = 0; tt < 4; ++tt)
                O[tt] = __builtin_amdgcn_mfma_f32_16x16x32_f16(pa, vb[kk][tt], O[tt], 0, 0, 0);
        }
    }

    // epilogue: unnormalized O + per-row (m, l)
    #pragma unroll
    for (int rr = 0; rr < 4; ++rr) {
        int lrow = l0 + wv * 16 + grp * 4 + rr;
        size_t prow = (size_t)(half * 32 + nh) * LQ + lrow;
        float* op = Op + prow * NE;
        #pragma unroll
        for (int tt = 0; tt < 4; ++tt)
            op[tt * 16 + r16] = O[tt][rr];
        if (r16 == 0) {
            Mp[prow] = m_i[rr];
            Lp[prow] = l_i[rr];
        }
    }
}

// ---------------- merge: combine the two split-K halves (exact) ----------------
__global__ __launch_bounds__(256) void sinattn_merge(
    const float* __restrict__ Op, const float* __restrict__ Mp,
    const float* __restrict__ Lp, float* __restrict__ out)
{
    int idx = blockIdx.x * 256 + threadIdx.x;   // ((n*L+l)*H+h)*E+e
    if (idx >= NB * LQ * NH * NE) return;
    int e = idx & 63;
    int h = (idx >> 6) & 7;
    int t = idx >> 9;
    int l = t % LQ;
    int n = t / LQ;
    int nh = (n << 3) | h;
    int row = nh * LQ + l;
    const int HOFF = 32 * LQ;

    float m0 = Mp[row],        m1 = Mp[HOFF + row];
    float l0 = Lp[row],        l1 = Lp[HOFF + row];
    float mm = fmaxf(m0, m1);
    float a0 = __expf(m0 - mm), a1 = __expf(m1 - mm);
    float denom = l0 * a0 + l1 * a1;
    float o0 = Op[(size_t)row * NE + e];
    float o1 = Op[(size_t)(HOFF + row) * NE + e];
    out[idx] = (o0 * a0 + o1 * a1) / denom;
}

extern "C" void kernel_launch(void* const* d_in, const int* in_sizes, int n_in,
                              void* d_out, int out_size, void* d_ws, size_t ws_size,
                              hipStream_t stream)
{
    const float* Q      = (const float*)d_in[0];
    const float* K      = (const float*)d_in[1];
    const float* V      = (const float*)d_in[2];
    const float* mask   = (const float*)d_in[3];
    const float* keylen = (const float*)d_in[4];
    const float* freqs  = (const float*)d_in[5];
    const float* offs   = (const float*)d_in[6];
    const float* gains  = (const float*)d_in[7];
    const float* gate   = (const float*)d_in[8];
    float* out = (float*)d_out;

    const size_t P = (size_t)NB * NH * LQ * ND;   // 4.72M f16 / plane
    f16* Qf = (f16*)d_ws;
    f16* Kf = Qf + P;
    f16* Vt = Kf + P;                             // 1.57M f16
    float* Op = (float*)(Vt + (size_t)NB * NH * NE * LQ);  // 2*32*768*64 f32
    float* Mp = Op + (size_t)2 * 32 * LQ * NE;
    float* Lp = Mp + (size_t)2 * 32 * LQ;

    sinattn_prepvt<<<1152, 256, 0, stream>>>(Q, K, V, freqs, offs, gains, gate,
                                             Qf, Kf, Vt);
    sinattn_flash<<<768, 256, 0, stream>>>(Qf, Kf, Vt, mask, keylen, Op, Mp, Lp);
    sinattn_merge<<<6144, 256, 0, stream>>>(Op, Mp, Lp, out);
}

// Round 9
// 124.345 us; speedup vs baseline: 1.4170x; 1.1050x over previous
//
#include <hip/hip_runtime.h>
#include <math.h>
#include <stdint.h>

#define NB 4
#define LQ 768
#define NH 8
#define NE 64
#define ND 192   // 3*E augmented feature dim
#define TEMP 0.125f

typedef _Float16 f16;
typedef __attribute__((ext_vector_type(8))) _Float16 f16x8;
typedef __attribute__((ext_vector_type(4))) float f32x4;

// Async global->LDS 16B: HW writes lds_base + lane*16. lds_base wave-uniform.
__device__ __forceinline__ void stage16(f16* lds_base, const f16* g, int lane) {
#if __has_builtin(__builtin_amdgcn_global_load_lds)
    __builtin_amdgcn_global_load_lds(
        (const __attribute__((address_space(1))) uint32_t*)g,
        (__attribute__((address_space(3))) uint32_t*)lds_base, 16, 0, 0);
#else
    *(uint4*)((char*)lds_base + lane * 16) = *(const uint4*)g;
#endif
}

// ---------------- fused prep (blocks 0..767) + V transpose (768..1151) ----------------
// Q' planes are pre-scaled by TEMP (exact, power of 2) so flash's QK output
// is already the scaled logit contribution.
__global__ __launch_bounds__(256) void sinattn_prepvt(
    const float* __restrict__ Q, const float* __restrict__ K,
    const float* __restrict__ V,
    const float* __restrict__ freqs, const float* __restrict__ offsets,
    const float* __restrict__ gains, const float* __restrict__ gate,
    f16* __restrict__ Qf, f16* __restrict__ Kf, f16* __restrict__ Vt)
{
    if (blockIdx.x < 768) {
        int idx = blockIdx.x * 256 + threadIdx.x;   // ((n*L+l)*8 + h)*8 + eg
        int eg = idx & 7, e0 = eg << 3;
        int h  = (idx >> 3) & 7;
        int t  = idx >> 6;                          // n*L + l
        int l  = t % LQ;
        int n  = t / LQ;
        int nh = (n << 3) | h;
        int he = (h << 6) | e0;

        const float* qp = Q + (size_t)idx * 8;
        const float* kp = K + (size_t)idx * 8;
        float4 q0 = *(const float4*)qp, q1 = *(const float4*)(qp + 4);
        float4 k0 = *(const float4*)kp, k1 = *(const float4*)(kp + 4);
        float qv[8] = {q0.x,q0.y,q0.z,q0.w, q1.x,q1.y,q1.z,q1.w};
        float kv[8] = {k0.x,k0.y,k0.z,k0.w, k1.x,k1.y,k1.z,k1.w};

        float4 fA = *(const float4*)(freqs   + he), fB = *(const float4*)(freqs   + he + 4);
        float4 oA = *(const float4*)(offsets + he), oB = *(const float4*)(offsets + he + 4);
        float4 gA = *(const float4*)(gains   + he), gB = *(const float4*)(gains   + he + 4);
        float4 tA = *(const float4*)(gate    + he), tB = *(const float4*)(gate    + he + 4);
        float fv[8] = {fA.x,fA.y,fA.z,fA.w, fB.x,fB.y,fB.z,fB.w};
        float ov[8] = {oA.x,oA.y,oA.z,oA.w, oB.x,oB.y,oB.z,oB.w};
        float gv[8] = {gA.x,gA.y,gA.z,gA.w, gB.x,gB.y,gB.z,gB.w};
        float tv[8] = {tA.x,tA.y,tA.z,tA.w, tB.x,tB.y,tB.z,tB.w};

        f16x8 oq0, oq1, oq2, ok0, ok1, ok2;
        float lf = (float)l;
        #pragma unroll
        for (int j = 0; j < 8; ++j) {
            float f  = 0.5f / (1.0f + __expf(-fv[j]));
            float gn = gv[j];
            float sp = (gn > 15.0f) ? gn : __logf(1.0f + __expf(gn));
            float gt = tv[j];
            float a  = (1.0f - gt) * sp * sp;
            float fh = __uint_as_float(__float_as_uint(f) & 0xFFFFF000u);
            float fl = f - fh;
            float t0 = lf * fh;
            float tr = t0 - floorf(t0);
            tr = __builtin_fmaf(lf, fl, tr);
            float pk = 6.28318530717958647f * tr;
            float pq = pk + ov[j];
            float sq = __sinf(pq), cq = __cosf(pq);
            float sk = __sinf(pk), ck = __cosf(pk);
            oq0[j] = (f16)(qv[j] * a * cq * TEMP);
            oq1[j] = (f16)(qv[j] * a * sq * TEMP);
            oq2[j] = (f16)(qv[j] * gt * TEMP);
            ok0[j] = (f16)(kv[j] * ck);
            ok1[j] = (f16)(kv[j] * sk);
            ok2[j] = (f16)(kv[j]);
        }
        size_t base = ((size_t)nh * LQ + l) * ND + e0;
        *(f16x8*)(Qf + base)          = oq0;
        *(f16x8*)(Qf + base + NE)     = oq1;
        *(f16x8*)(Qf + base + 2*NE)   = oq2;
        *(f16x8*)(Kf + base)          = ok0;
        *(f16x8*)(Kf + base + NE)     = ok1;
        *(f16x8*)(Kf + base + 2*NE)   = ok2;
    } else {
        __shared__ f16 tile[64][72];
        int b = blockIdx.x - 768;
        int st = b % 12, nh = b / 12;
        int n = nh >> 3, h = nh & 7;
        int s0 = st * 64;
        int tid = threadIdx.x;

        int sl = tid >> 2, e0 = (tid & 3) << 4;
        const float4* vp = (const float4*)(V + ((size_t)(n * LQ + s0 + sl) * NH + h) * NE + e0);
        float4 a0 = vp[0], a1 = vp[1], a2 = vp[2], a3 = vp[3];
        float vv[16] = { a0.x,a0.y,a0.z,a0.w, a1.x,a1.y,a1.z,a1.w,
                         a2.x,a2.y,a2.z,a2.w, a3.x,a3.y,a3.z,a3.w };
        #pragma unroll
        for (int j = 0; j < 16; ++j) tile[e0 + j][sl] = (f16)vv[j];
        __syncthreads();

        int er = tid >> 2, sc = tid & 3;
        f16* op = Vt + ((size_t)nh * NE + er) * LQ + s0 + sc * 16;
        *(uint4*)op       = *(const uint4*)&tile[er][sc * 16];
        *(uint4*)(op + 8) = *(const uint4*)&tile[er][sc * 16 + 8];
    }
}

// ---------------- flash: dbuf DMA, ONE barrier/chunk, grid 512 = 2 blocks/CU ----------------
// 32 nh x 16 q-tiles(48 rows). block = 192 threads (3 waves x 16 rows).
// Double-buffered sK: the single top-of-iteration __syncthreads (vmcnt drain)
// proves both "chunk c landed" and "old readers of sK[c+1]'s buffer done".
// Row sums via mfma(P, ones) — no sum shfl chain. V/mask/keylen from L2.
// Writes normalized output directly (no split-K, no merge).
__global__ __launch_bounds__(192, 2) void sinattn_flash(
    const f16* __restrict__ Qf, const f16* __restrict__ Kf, const f16* __restrict__ Vt,
    const float* __restrict__ mask, const float* __restrict__ keylen,
    float* __restrict__ out)
{
    __shared__ __attribute__((aligned(16))) f16 sK[2][64 * 24 * 8];  // 24 KB each
    __shared__ __attribute__((aligned(16))) f16 sP[3][16 * 68];      // 6.4 KB

    int tid  = threadIdx.x;
    int wv   = tid >> 6;                              // 0..2
    int wvu  = __builtin_amdgcn_readfirstlane(wv);
    int lane = tid & 63;
    int grp  = lane >> 4;
    int r16  = lane & 15;
    int swz  = r16 & 7;

    int bid = blockIdx.x;
    int nh  = bid & 31;           // XCD-local: bid%8 == nh%8
    int lt  = bid >> 5;           // 0..15
    int n   = nh >> 3;
    int l0  = lt * 48;

    const f16* Kb = Kf + (size_t)nh * LQ * ND;
    const f16* Vb = Vt + (size_t)nh * NE * LQ;

    // per-lane swizzled global offsets for K staging (1536 16B-chunks, 8/thread)
    int goffK[8];
    #pragma unroll
    for (int i = 0; i < 8; ++i) {
        int p = i * 192 + wv * 64 + lane;
        int r = p / 24, c = p - r * 24;
        int cl = (c & ~7) | ((c & 7) ^ (r & 7));
        goffK[i] = r * ND + cl * 8;
    }

    // issue chunk 0 DMA into buffer 0 (lands while qf loads / init run)
    #pragma unroll
    for (int i = 0; i < 8; ++i)
        stage16(&sK[0][(i * 192 + wvu * 64) * 8], Kb + goffK[i], lane);

    // Q fragments (A-layout: row=r16, k=d0*32+grp*8+j), TEMP pre-folded
    f16x8 qf[6];
    {
        size_t rbase = ((size_t)nh * LQ + l0 + wv * 16 + r16) * ND + grp * 8;
        #pragma unroll
        for (int d0 = 0; d0 < 6; ++d0)
            qf[d0] = *(const f16x8*)(Qf + rbase + d0 * 32);
    }

    f16x8 ones;
    #pragma unroll
    for (int j = 0; j < 8; ++j) ones[j] = (f16)1.0f;

    float m_i[4], l_i[4];
    f32x4 O[4];
    #pragma unroll
    for (int rr = 0; rr < 4; ++rr) { m_i[rr] = -INFINITY; l_i[rr] = 0.f; }
    #pragma unroll
    for (int tt = 0; tt < 4; ++tt)
        #pragma unroll
        for (int rr = 0; rr < 4; ++rr) O[tt][rr] = 0.f;

    for (int c = 0; c < 12; ++c) {
        int cur = c & 1;
        int s0  = c * 64;
        __syncthreads();   // ONE barrier: chunk c landed + old readers of other buf done

        if (c < 11) {      // DMA chunk c+1 into the other buffer; full iter to land
            const f16* kg = Kb + (size_t)(s0 + 64) * ND;
            #pragma unroll
            for (int i = 0; i < 8; ++i)
                stage16(&sK[cur ^ 1][(i * 192 + wvu * 64) * 8], kg + goffK[i], lane);
        }

        // early-issue global loads for this chunk (consumed after QK)
        float klv[4];
        #pragma unroll
        for (int j = 0; j < 4; ++j) klv[j] = TEMP * keylen[n * LQ + s0 + j * 16 + r16];
        float mreg[4][4];
        #pragma unroll
        for (int rr = 0; rr < 4; ++rr) {
            int lrow = l0 + wv * 16 + grp * 4 + rr;
            #pragma unroll
            for (int j = 0; j < 4; ++j)
                mreg[rr][j] = mask[lrow * LQ + s0 + j * 16 + r16];
        }
        f16x8 vb[2][4];
        #pragma unroll
        for (int kk = 0; kk < 2; ++kk)
            #pragma unroll
            for (int tt = 0; tt < 4; ++tt)
                vb[kk][tt] = *(const f16x8*)(Vb + (size_t)(tt * 16 + r16) * LQ
                                             + s0 + kk * 32 + grp * 8);

        // S(scaled) = (TEMP*Q').K'^T from LDS
        f32x4 st[4];
        #pragma unroll
        for (int j = 0; j < 4; ++j)
            #pragma unroll
            for (int rr = 0; rr < 4; ++rr) st[j][rr] = 0.f;
        #pragma unroll
        for (int d0 = 0; d0 < 6; ++d0) {
            #pragma unroll
            for (int j = 0; j < 4; ++j) {
                int cc = d0 * 4 + grp;
                int cl = (cc & ~7) | ((cc & 7) ^ swz);
                f16x8 bf = *(const f16x8*)&sK[cur][((j * 16 + r16) * 24 + cl) * 8];
                st[j] = __builtin_amdgcn_mfma_f32_16x16x32_f16(qf[d0], bf, st[j], 0, 0, 0);
            }
        }

        // online softmax (C layout: col=r16+16j, row=grp*4+rr); sum via MFMA below
        float alpha[4];
        #pragma unroll
        for (int rr = 0; rr < 4; ++rr) {
            float lg[4];
            float mx = -INFINITY;
            #pragma unroll
            for (int j = 0; j < 4; ++j) {
                lg[j] = __builtin_fmaf(TEMP, mreg[rr][j], st[j][rr] + klv[j]);
                mx = fmaxf(mx, lg[j]);
            }
            #pragma unroll
            for (int d = 1; d < 16; d <<= 1) mx = fmaxf(mx, __shfl_xor(mx, d));
            float mnew = fmaxf(m_i[rr], mx);
            alpha[rr]  = __expf(m_i[rr] - mnew);
            m_i[rr]    = mnew;
            #pragma unroll
            for (int j = 0; j < 4; ++j)
                sP[wv][(grp * 4 + rr) * 68 + j * 16 + r16] = (f16)__expf(lg[j] - mnew);
        }
        #pragma unroll
        for (int tt = 0; tt < 4; ++tt)
            #pragma unroll
            for (int rr = 0; rr < 4; ++rr) O[tt][rr] *= alpha[rr];

        // O += P.V ; row-sums of P via mfma(P, ones) (C-layout reg rr = row grp*4+rr)
        f32x4 rs;
        #pragma unroll
        for (int rr = 0; rr < 4; ++rr) rs[rr] = 0.f;
        #pragma unroll
        for (int kk = 0; kk < 2; ++kk) {
            f16x8 pa = *(const f16x8*)&sP[wv][r16 * 68 + kk * 32 + grp * 8];
            rs = __builtin_amdgcn_mfma_f32_16x16x32_f16(pa, ones, rs, 0, 0, 0);
            #pragma unroll
            for (int tt = 0; tt < 4; ++tt)
                O[tt] = __builtin_amdgcn_mfma_f32_16x16x32_f16(pa, vb[kk][tt], O[tt], 0, 0, 0);
        }
        #pragma unroll
        for (int rr = 0; rr < 4; ++rr)
            l_i[rr] = __builtin_fmaf(l_i[rr], alpha[rr], rs[rr]);
    }

    // epilogue: normalize, write out[n][l][h][e]
    #pragma unroll
    for (int rr = 0; rr < 4; ++rr) {
        float inv = 1.0f / l_i[rr];
        int lrow = l0 + wv * 16 + grp * 4 + rr;
        float* op = out + ((size_t)(n * LQ + lrow) * NH + (nh & 7)) * NE;
        #pragma unroll
        for (int tt = 0; tt < 4; ++tt)
            op[tt * 16 + r16] = O[tt][rr] * inv;
    }
}

extern "C" void kernel_launch(void* const* d_in, const int* in_sizes, int n_in,
                              void* d_out, int out_size, void* d_ws, size_t ws_size,
                              hipStream_t stream)
{
    const float* Q      = (const float*)d_in[0];
    const float* K      = (const float*)d_in[1];
    const float* V      = (const float*)d_in[2];
    const float* mask   = (const float*)d_in[3];
    const float* keylen = (const float*)d_in[4];
    const float* freqs  = (const float*)d_in[5];
    const float* offs   = (const float*)d_in[6];
    const float* gains  = (const float*)d_in[7];
    const float* gate   = (const float*)d_in[8];
    float* out = (float*)d_out;

    const size_t P = (size_t)NB * NH * LQ * ND;   // 4.72M f16 / plane
    f16* Qf = (f16*)d_ws;
    f16* Kf = Qf + P;
    f16* Vt = Kf + P;                             // 1.57M f16

    sinattn_prepvt<<<1152, 256, 0, stream>>>(Q, K, V, freqs, offs, gains, gate,
                                             Qf, Kf, Vt);
    sinattn_flash<<<512, 192, 0, stream>>>(Qf, Kf, Vt, mask, keylen, out);
}